// Round 3
// baseline (1775.896 us; speedup 1.0000x reference)
//
#include <hip/hip_runtime.h>

typedef __attribute__((ext_vector_type(8))) short bf16x8;
typedef __attribute__((ext_vector_type(4))) float f32x4;
typedef __attribute__((ext_vector_type(4))) ushort u16x4;

__device__ __forceinline__ ushort f2b(float v) {
    union { float f; unsigned u; } x; x.f = v;
    unsigned r = x.u + 0x7fffu + ((x.u >> 16) & 1u);
    return (ushort)(r >> 16);
}
__device__ __forceinline__ float b2f(ushort b) {
    union { float f; unsigned u; } x; x.u = ((unsigned)b) << 16; return x.f;
}

// async global->LDS 16B per lane; LDS dest = wave-uniform base + lane*16
__device__ __forceinline__ void gl_lds16(const void* g, void* l) {
    __builtin_amdgcn_global_load_lds(
        (__attribute__((address_space(1))) void*)(g),
        (__attribute__((address_space(3))) void*)(l), 16, 0, 0);
}

// ---------------- prep kernels ----------------

__global__ void k_split(const float* __restrict__ src, ushort* __restrict__ hi,
                        ushort* __restrict__ lo, int rows, int K, int Kpad) {
    long total = (long)rows * Kpad;
    for (long idx = (long)blockIdx.x * 256 + threadIdx.x; idx < total;
         idx += (long)gridDim.x * 256) {
        int r = (int)(idx / Kpad), c = (int)(idx % Kpad);
        float v = (c < K) ? src[(long)r * K + c] : 0.f;
        ushort h = f2b(v);
        hi[idx] = h;
        if (lo) lo[idx] = f2b(v - b2f(h));
    }
}

// Wc[n][k] = sum_d qkvW[n][d] * fl1W[d][k];  bc[n] = sum_d qkvW[n][d] * fl1b[d]
__global__ void k_wc(const float* __restrict__ qkvW, const float* __restrict__ fl1W,
                     const float* __restrict__ fl1b, float* __restrict__ Wc,
                     float* __restrict__ bc) {
    int idx = blockIdx.x * 256 + threadIdx.x;
    if (idx >= 384 * 1024) return;
    int n = idx >> 10, k = idx & 1023;
    float s = 0.f;
    #pragma unroll 8
    for (int d = 0; d < 128; ++d) s += qkvW[n * 128 + d] * fl1W[d * 1024 + k];
    Wc[idx] = s;
    if (k == 0) {
        float sb = 0.f;
        #pragma unroll 8
        for (int d = 0; d < 128; ++d) sb += qkvW[n * 128 + d] * fl1b[d];
        bc[n] = sb;
    }
}

__global__ void k_sk(const float* __restrict__ fs, const float* __restrict__ fW,
                     const float* __restrict__ fb, float* __restrict__ sk) {
    int m = blockIdx.x * 256 + threadIdx.x;
    if (m >= 12800) return;
    int b = m / 50, i = m % 50;
    float s = fb[i];
    #pragma unroll 4
    for (int c = 0; c < 36; ++c) s += fs[b * 36 + c] * fW[i * 36 + c];
    sk[m] = s;
}

// GRU(10->10): one wave (=one block of 64) per batch element -> 256 CUs covered
__global__ void k_gru(const float* __restrict__ noise, const float* __restrict__ Wih,
                      const float* __restrict__ Whh, const float* __restrict__ bih,
                      const float* __restrict__ bhh, float* __restrict__ aux) {
    int lane = threadIdx.x & 63;
    int b = blockIdx.x;
    if (b >= 256) return;
    float wih[10] = {}, whh[10] = {};
    float bi = 0.f, bh = 0.f;
    if (lane < 30) {
        #pragma unroll
        for (int c = 0; c < 10; ++c) { wih[c] = Wih[lane * 10 + c]; whh[c] = Whh[lane * 10 + c]; }
        bi = bih[lane]; bh = bhh[lane];
    }
    float h = 0.f;
    for (int t = 0; t < 50; ++t) {
        float xr = (lane < 10) ? noise[(b * 50 + t) * 10 + lane] : 0.f;
        float gi = bi, gh = bh;
        #pragma unroll
        for (int c = 0; c < 10; ++c) {
            float xc = __shfl(xr, c, 64);
            float hc = __shfl(h, c, 64);
            gi += wih[c] * xc; gh += whh[c] * hc;
        }
        float siz = __shfl(gi, lane + 10, 64), shz = __shfl(gh, lane + 10, 64);
        float sin_ = __shfl(gi, lane + 20, 64), shn = __shfl(gh, lane + 20, 64);
        float r = 1.f / (1.f + expf(-(gi + gh)));
        float z = 1.f / (1.f + expf(-(siz + shz)));
        float n = tanhf(sin_ + r * shn);
        float hn = (1.f - z) * n + z * h;
        if (lane < 10) { h = hn; aux[(b * 50 + t) * 10 + lane] = tanhf(hn); }
    }
}

__global__ void k_xbuild(const float* __restrict__ input, const float* __restrict__ aux,
                         const float* __restrict__ sk, ushort* __restrict__ xhi,
                         ushort* __restrict__ xlo, long M) {
    long idx = (long)blockIdx.x * 256 + threadIdx.x;
    if (idx >= M * 288) return;
    int m = (int)(idx / 288), c = (int)(idx % 288);
    float v;
    if (c < 256) v = input[(long)m * 256 + c];
    else if (c < 266) v = aux[m * 10 + (c - 256)];
    else if (c == 266) v = sk[m];
    else v = 0.f;
    ushort h = f2b(v);
    xhi[idx] = h;
    xlo[idx] = f2b(v - b2f(h));
}

// ---------------- split-bf16 MFMA GEMM, global_load_lds staging ----------------
// XCD-aware bijective remap (m204): each XCD gets a contiguous wgid range,
// ordered x-fast/y-slow so its B working set stays L2-resident and each
// A-tile is reused by consecutive same-XCD blocks.
template <int MODE>
__global__ __launch_bounds__(256, 3) void k_gemm(
    const ushort* __restrict__ Ahi, const ushort* __restrict__ Alo,
    const ushort* __restrict__ Bhi, const ushort* __restrict__ Blo,
    int N, int K,
    float* outF, ushort* outHi, ushort* outLo,
    const float* __restrict__ bias,
    const float* __restrict__ bng, const float* __restrict__ bnb,
    const float* __restrict__ bnm, const float* __restrict__ bnv,
    const ushort* resHi, const ushort* resLo) {
    __shared__ __align__(16) ushort S[4][128][32];   // Ah, Al, Bh, Bl : 32 KB
    int t = threadIdx.x;
    // XCD swizzle
    int flat = blockIdx.y * gridDim.x + blockIdx.x;
    int nwg = gridDim.x * gridDim.y;
    int q = nwg >> 3, r = nwg & 7;
    int xcd = flat & 7, seq = flat >> 3;
    int wgid = (xcd < r ? xcd * (q + 1) : r * (q + 1) + (xcd - r) * q) + seq;
    int bx = wgid % gridDim.x, by = wgid / gridDim.x;
    int m0 = by * 128, n0 = bx * 128;
    int w = t >> 6, lane = t & 63;
    int wm = w >> 1, wn = w & 1;
    int lo16 = lane & 15, hi4 = lane >> 4;

    const int srow = lane >> 2;
    const int skoff = ((lane & 3) ^ (srow & 3)) * 8;   // elements
    const int slot8 = (hi4 ^ (lo16 & 3)) * 8;

    f32x4 acc[4][4];
    #pragma unroll
    for (int i = 0; i < 4; ++i)
        #pragma unroll
        for (int j = 0; j < 4; ++j) acc[i][j] = f32x4{0.f, 0.f, 0.f, 0.f};

    const int nk = K / 32;
    for (int kt = 0; kt < nk; ++kt) {
        const int kb = kt * 32;
        #pragma unroll
        for (int i = 0; i < 2; ++i) {
            int rg = w * 32 + i * 16;              // wave-uniform row-group base
            long ga = (long)(m0 + rg + srow) * K + kb + skoff;
            long gb = (long)(n0 + rg + srow) * K + kb + skoff;
            gl_lds16(&Ahi[ga], &S[0][rg][0]);
            gl_lds16(&Alo[ga], &S[1][rg][0]);
            gl_lds16(&Bhi[gb], &S[2][rg][0]);
            gl_lds16(&Blo[gb], &S[3][rg][0]);
        }
        __syncthreads();
        bf16x8 ah[4], al[4], bh[4], bl[4];
        #pragma unroll
        for (int m = 0; m < 4; ++m) {
            int row = wm * 64 + m * 16 + lo16;
            ah[m] = *(const bf16x8*)&S[0][row][slot8];
            al[m] = *(const bf16x8*)&S[1][row][slot8];
        }
        #pragma unroll
        for (int n = 0; n < 4; ++n) {
            int col = wn * 64 + n * 16 + lo16;
            bh[n] = *(const bf16x8*)&S[2][col][slot8];
            bl[n] = *(const bf16x8*)&S[3][col][slot8];
        }
        #pragma unroll
        for (int m = 0; m < 4; ++m)
            #pragma unroll
            for (int n = 0; n < 4; ++n) {
                acc[m][n] = __builtin_amdgcn_mfma_f32_16x16x32_bf16(ah[m], bh[n], acc[m][n], 0, 0, 0);
                acc[m][n] = __builtin_amdgcn_mfma_f32_16x16x32_bf16(ah[m], bl[n], acc[m][n], 0, 0, 0);
                acc[m][n] = __builtin_amdgcn_mfma_f32_16x16x32_bf16(al[m], bh[n], acc[m][n], 0, 0, 0);
            }
        __syncthreads();
    }

    #pragma unroll
    for (int n = 0; n < 4; ++n) {
        int gn = n0 + wn * 64 + n * 16 + lo16;
        float bv = bias ? bias[gn] : 0.f;
        float sc = 1.f, sh = 0.f;
        if (MODE >= 1) { sc = bng[gn] * rsqrtf(bnv[gn] + 1e-5f); sh = bnb[gn] - bnm[gn] * sc; }
        #pragma unroll
        for (int m = 0; m < 4; ++m)
            #pragma unroll
            for (int r2 = 0; r2 < 4; ++r2) {
                int gm = m0 + wm * 64 + m * 16 + hi4 * 4 + r2;
                long o = (long)gm * N + gn;
                float v = acc[m][n][r2] + bv;
                if (MODE >= 1) v = fmaxf(v * sc + sh, 0.f);
                if (MODE == 2) v += b2f(resHi[o]) + b2f(resLo[o]);
                if (outF) outF[o] = v;
                if (outHi) {
                    ushort hb = f2b(v);
                    outHi[o] = hb;
                    outLo[o] = f2b(v - b2f(hb));
                }
            }
    }
}

// ---------------- pos (fl2): wave-per-row, vectorized hi/lo loads ----------------
__global__ void k_fl2(const ushort* __restrict__ hA, const ushort* __restrict__ lA,
                      const float* __restrict__ W, const float* __restrict__ bias,
                      float* __restrict__ pos) {
    int w = threadIdx.x >> 6, lane = threadIdx.x & 63;
    int m = blockIdx.x * 4 + w;
    float a0 = 0.f, a1 = 0.f, a2 = 0.f;
    for (int k0 = lane * 4; k0 < 1024; k0 += 256) {
        long o = (long)m * 1024 + k0;
        u16x4 hv = *(const u16x4*)&hA[o];
        u16x4 lv = *(const u16x4*)&lA[o];
        f32x4 w0 = *(const f32x4*)&W[k0];
        f32x4 w1 = *(const f32x4*)&W[1024 + k0];
        f32x4 w2 = *(const f32x4*)&W[2048 + k0];
        #pragma unroll
        for (int e = 0; e < 4; ++e) {
            float x = b2f(hv[e]) + b2f(lv[e]);
            a0 += x * w0[e]; a1 += x * w1[e]; a2 += x * w2[e];
        }
    }
    #pragma unroll
    for (int off = 32; off; off >>= 1) {
        a0 += __shfl_xor(a0, off, 64);
        a1 += __shfl_xor(a1, off, 64);
        a2 += __shfl_xor(a2, off, 64);
    }
    if (lane == 0) {
        pos[m * 3 + 0] = a0 + bias[0];
        pos[m * 3 + 1] = a1 + bias[1];
        pos[m * 3 + 2] = a2 + bias[2];
    }
}

// ---------------- fused attention (+rel_emb +fl3) per (b,i) block ----------------
// R8: round-2 structure with a unified-register-file-safe plan.
// gfx950 unified VGPR+AGPR budget; launch_bounds(256,3) caps ~170/wave.
// Round-2's a_x[4][4] hoist (64 VGPR) + 48 AGPR acc blew the cap -> forced
// scratch spill (WRITE_SIZE 281MB). Fix: GEMM1 tiled 2x2 across waves
// (wave (wm,wn): rows wm*32..+32 x cols wn*32..+32 of each eighth) so the
// hoist is a_x[2][4] = 32 VGPR. Cost: GEMM1 B-frags loaded 2x per block
// (8 instead of 4 dwordx4/wave/e8, L1-hot, each reused 2x).
//  - h1/rel prologue in registers (verified R6/R7), REL wave-private writes.
//  - HE double-buffered: ONE barrier per e8. Barriers ~12. LDS 32KB.
// LDS map:
//   [0,16384)      REL[64][256B pitch], swz byte = j*256 + ((d*2)^((j&15)<<4))
//   [16384,32768)  XS (one-time, dies at hoist) then HE ping-pong
//                  (2 x 64 rows x 128B, swz (c*2)^((r&7)<<4))
//   aggF f32[128] overlaid at 16384 after main loop.
__global__ __launch_bounds__(256, 3) void k_attn(
    const float* __restrict__ qkv, const float* __restrict__ posb,
    const ushort* __restrict__ W1b, const ushort* __restrict__ W2b,
    const float* __restrict__ b1, const ushort* __restrict__ pW2b,
    const float* __restrict__ pW1, const float* __restrict__ pb1,
    const float* __restrict__ pb2,
    const float* __restrict__ fl3W, const float* __restrict__ fl3b,
    float* __restrict__ out, long mbase) {
    __shared__ __align__(16) char smem[32768];
    // XCD-aware swizzle: gridDim.x % 8 == 0 always (12800 or 6400)
    int cpx = gridDim.x >> 3;
    int biL = (blockIdx.x & 7) * cpx + (blockIdx.x >> 3);
    int bL = biL / 50;
    int t = threadIdx.x, w = t >> 6, lane = t & 63;
    int lo16 = lane & 15, hi4 = lane >> 4;
    int wm = w >> 1, wn = w & 1;

    // ---- phase 0a: h1 fragments in registers (row-split, wave-private) ----
    // lane holds h1[jrow][k] for jrow = w*16+lo16, k = kt*32 + hi4*8 + e
    bf16x8 h_a[2];
    {
        const int jrow = w * 16 + lo16;
        const bool jvalid = jrow < 50;
        float pi0 = posb[biL * 3], pi1 = posb[biL * 3 + 1], pi2 = posb[biL * 3 + 2];
        float d0 = 0.f, d1 = 0.f, d2 = 0.f;
        if (jvalid) {
            int pj = (bL * 50 + jrow) * 3;
            d0 = pi0 - posb[pj]; d1 = pi1 - posb[pj + 1]; d2 = pi2 - posb[pj + 2];
        }
        #pragma unroll
        for (int kt = 0; kt < 2; ++kt)
            #pragma unroll
            for (int e = 0; e < 8; ++e) {
                int ke = kt * 32 + hi4 * 8 + e;
                float v = 0.f;
                if (jvalid)
                    v = fmaxf(pb1[ke] + pW1[ke * 3] * d0 + pW1[ke * 3 + 1] * d1
                              + pW1[ke * 3 + 2] * d2, 0.f);
                h_a[kt][e] = (short)f2b(v);
            }
    }

    // ---- phase 0b: rel rows for own 16 j (MFMA K=64) -> REL (wave-private) ----
    {
        f32x4 racc[8];
        #pragma unroll
        for (int n = 0; n < 8; ++n) racc[n] = f32x4{0.f, 0.f, 0.f, 0.f};
        #pragma unroll
        for (int kt = 0; kt < 2; ++kt) {
            int k0 = kt * 32 + hi4 * 8;
            #pragma unroll
            for (int n = 0; n < 8; ++n) {
                bf16x8 bv = *(const bf16x8*)&pW2b[(n * 16 + lo16) * 64 + k0];
                racc[n] = __builtin_amdgcn_mfma_f32_16x16x32_bf16(h_a[kt], bv, racc[n], 0, 0, 0);
            }
        }
        #pragma unroll
        for (int n = 0; n < 8; ++n) {
            int col = n * 16 + lo16;
            float pb = pb2[col];
            #pragma unroll
            for (int r = 0; r < 4; ++r) {
                int j = w * 16 + hi4 * 4 + r;
                *(ushort*)(smem + j * 256 + ((col * 2) ^ ((j & 15) << 4))) =
                    f2b(racc[n][r] + pb);
            }
        }
    }
    __syncthreads();   // REL complete (X-build reads rows written by other waves)

    // ---- phase 1: X = q_i - k_j + rel -> XS @16K (bf16 swz); rows 50..63 zero ----
    #pragma unroll
    for (int cc = 0; cc < 4; ++cc) {
        int c = cc * 256 + t;
        int row = c >> 4, g = c & 15;
        bf16x8 tv;
        if (row < 50) {
            long kq = (long)biL * 384;
            long kk = (long)(bL * 50 + row) * 384 + 128;
            bf16x8 rv = *(const bf16x8*)(smem + row * 256 + ((g * 16) ^ ((row & 15) << 4)));
            #pragma unroll
            for (int e = 0; e < 8; ++e) {
                int col = g * 8 + e;
                float v = qkv[kq + col] - qkv[kk + col] + b2f((ushort)rv[e]);
                tv[e] = (short)f2b(v);
            }
        } else {
            #pragma unroll
            for (int e = 0; e < 8; ++e) tv[e] = 0;
        }
        *(bf16x8*)(smem + 16384 + row * 256 + ((g * 16) ^ ((row & 15) << 4))) = tv;
    }
    __syncthreads();   // XS complete

    // ---- one-time A hoist: wave's 32 rows of X into registers (32 VGPR) ----
    bf16x8 a_x[2][4];
    #pragma unroll
    for (int m = 0; m < 2; ++m)
        #pragma unroll
        for (int kt = 0; kt < 4; ++kt) {
            int row = wm * 32 + m * 16 + lo16;
            int k0 = kt * 32 + hi4 * 8;
            a_x[m][kt] = *(const bf16x8*)(smem + 16384 + row * 256 +
                          ((k0 * 2) ^ ((row & 15) << 4)));
        }
    __syncthreads();   // all waves done reading XS; HE may now overwrite it

    // ---- main loop: 8 eighths of H, 1 barrier each (HE double-buffered) ----
    f32x4 acc2[4][2];
    #pragma unroll
    for (int m = 0; m < 4; ++m)
        #pragma unroll
        for (int n = 0; n < 2; ++n) acc2[m][n] = f32x4{0.f, 0.f, 0.f, 0.f};

    #pragma unroll 1
    for (int e8 = 0; e8 < 8; ++e8) {
        char* HEb = smem + 16384 + (e8 & 1) * 8192;
        // GEMM1: wave (wm,wn) -> rows wm*32..+32, cols wn*32..+32 of this eighth.
        // A from registers; each B-frag reused 2x (m=0,1).
        f32x4 acc1[2][2];
        #pragma unroll
        for (int m = 0; m < 2; ++m)
            #pragma unroll
            for (int n = 0; n < 2; ++n) acc1[m][n] = f32x4{0.f, 0.f, 0.f, 0.f};
        __builtin_amdgcn_s_setprio(1);
        #pragma unroll
        for (int kt = 0; kt < 4; ++kt) {
            int k0 = kt * 32 + hi4 * 8;
            #pragma unroll
            for (int n = 0; n < 2; ++n) {
                int col = e8 * 64 + wn * 32 + n * 16 + lo16;
                bf16x8 bv = *(const bf16x8*)&W1b[col * 128 + k0];
                #pragma unroll
                for (int m = 0; m < 2; ++m)
                    acc1[m][n] = __builtin_amdgcn_mfma_f32_16x16x32_bf16(a_x[m][kt], bv, acc1[m][n], 0, 0, 0);
            }
        }
        __builtin_amdgcn_s_setprio(0);
        // bias + relu -> HE[buf] (wave's 32x32 quadrant)
        #pragma unroll
        for (int n = 0; n < 2; ++n) {
            int ch = wn * 32 + n * 16 + lo16;
            float bb = b1[e8 * 64 + ch];
            #pragma unroll
            for (int m = 0; m < 2; ++m)
                #pragma unroll
                for (int r = 0; r < 4; ++r) {
                    int row = wm * 32 + m * 16 + hi4 * 4 + r;
                    float v = fmaxf(acc1[m][n][r] + bb, 0.f);
                    *(ushort*)(HEb + row * 128 + ((ch * 2) ^ ((row & 7) << 4))) = f2b(v);
                }
        }
        __syncthreads();   // HE[buf] complete; dbuf makes overwrite 2 iters out safe
        // GEMM2 partial: K chunk [e8*64, e8*64+64)
        #pragma unroll
        for (int kt2 = 0; kt2 < 2; ++kt2) {
            bf16x8 af[4];
            #pragma unroll
            for (int m = 0; m < 4; ++m) {
                int row = m * 16 + lo16;
                af[m] = *(const bf16x8*)(HEb + row * 128 +
                          (((kt2 * 32 + hi4 * 8) * 2) ^ ((row & 7) << 4)));
            }
            __builtin_amdgcn_s_setprio(1);
            #pragma unroll
            for (int n = 0; n < 2; ++n) {
                int col = w * 32 + n * 16 + lo16;
                int gk = e8 * 64 + kt2 * 32 + hi4 * 8;
                bf16x8 bfv = *(const bf16x8*)&W2b[(long)col * 512 + gk];
                #pragma unroll
                for (int m = 0; m < 4; ++m)
                    acc2[m][n] = __builtin_amdgcn_mfma_f32_16x16x32_bf16(af[m], bfv, acc2[m][n], 0, 0, 0);
            }
            __builtin_amdgcn_s_setprio(0);
        }
    }

    // ---- softmax over j + agg (v_ij = v + rel, rel from REL @0) ----
    float outv[2];
    #pragma unroll
    for (int n = 0; n < 2; ++n) {
        float mx = -1e30f;
        #pragma unroll
        for (int m = 0; m < 4; ++m)
            #pragma unroll
            for (int r = 0; r < 4; ++r) {
                int j = m * 16 + hi4 * 4 + r;
                if (j < 50) mx = fmaxf(mx, acc2[m][n][r]);
            }
        mx = fmaxf(mx, __shfl_xor(mx, 16, 64));
        mx = fmaxf(mx, __shfl_xor(mx, 32, 64));
        float e[4][4];
        float sum = 0.f;
        #pragma unroll
        for (int m = 0; m < 4; ++m)
            #pragma unroll
            for (int r = 0; r < 4; ++r) {
                int j = m * 16 + hi4 * 4 + r;
                float ev = (j < 50) ? __expf(acc2[m][n][r] - mx) : 0.f;
                e[m][r] = ev; sum += ev;
            }
        sum += __shfl_xor(sum, 16, 64);
        sum += __shfl_xor(sum, 32, 64);
        float inv = 1.f / sum;
        int col = w * 32 + n * 16 + lo16;
        float ag = 0.f;
        #pragma unroll
        for (int m = 0; m < 4; ++m)
            #pragma unroll
            for (int r = 0; r < 4; ++r) {
                int j = m * 16 + hi4 * 4 + r;
                if (j < 50) {
                    float rl = b2f(*(const ushort*)(smem + j * 256 +
                                  ((col * 2) ^ ((j & 15) << 4))));
                    float vv = qkv[(long)(bL * 50 + j) * 384 + 256 + col] + rl;
                    ag += e[m][r] * inv * vv;
                }
            }
        ag += __shfl_xor(ag, 16, 64);
        ag += __shfl_xor(ag, 32, 64);
        outv[n] = ag;
    }
    float* aggF = (float*)(smem + 16384);
    if (hi4 == 0) {
        aggF[w * 32 + lo16] = outv[0];
        aggF[w * 32 + 16 + lo16] = outv[1];
    }
    __syncthreads();

    // fused fl3 + tanh
    if (t < 36) {
        float s = fl3b[t];
        const float* wf = &fl3W[t * 128];
        #pragma unroll 8
        for (int d = 0; d < 128; ++d) s += aggF[d] * wf[d];
        out[(mbase + biL) * 36 + t] = tanhf(s);
    }
}

// ---------------- launch ----------------
struct Bufs {
    float *sk, *aux, *qkvF, *posb, *WcF, *bc;
    ushort *xh, *xl, *actAh, *actAl, *actBh, *actBl;
    ushort *l0Wh, *l0Wl, *resWh, *resWl, *Wch, *Wcl, *aW1b, *aW2b, *pW2b;
};

static size_t plan_ws(char* ws, long MCr, Bufs& B) {
    size_t off = 0;
    auto alloc = [&](size_t n) { char* p = ws + off; off += (n + 255) & ~(size_t)255; return p; };
    B.sk    = (float*) alloc(12800L * 4);
    B.aux   = (float*) alloc(128000L * 4);
    B.xh    = (ushort*)alloc((size_t)MCr * 288 * 2);
    B.xl    = (ushort*)alloc((size_t)MCr * 288 * 2);
    B.actAh = (ushort*)alloc((size_t)MCr * 1024 * 2);
    B.actAl = (ushort*)alloc((size_t)MCr * 1024 * 2);
    B.actBh = (ushort*)alloc((size_t)MCr * 1024 * 2);
    B.actBl = (ushort*)alloc((size_t)MCr * 1024 * 2);
    B.qkvF  = (float*) alloc((size_t)MCr * 384 * 4);
    B.posb  = (float*) alloc((size_t)MCr * 3 * 4);
    B.l0Wh  = (ushort*)alloc(1024L * 288 * 2);
    B.l0Wl  = (ushort*)alloc(1024L * 288 * 2);
    B.resWh = (ushort*)alloc(6144L * 1024 * 2);
    B.resWl = (ushort*)alloc(6144L * 1024 * 2);
    B.WcF   = (float*) alloc(384L * 1024 * 4);
    B.Wch   = (ushort*)alloc(384L * 1024 * 2);
    B.Wcl   = (ushort*)alloc(384L * 1024 * 2);
    B.bc    = (float*) alloc(384L * 4);
    B.aW1b  = (ushort*)alloc(512L * 128 * 2);
    B.aW2b  = (ushort*)alloc(128L * 512 * 2);
    B.pW2b  = (ushort*)alloc(128L * 64 * 2);
    return off;
}

extern "C" void kernel_launch(void* const* d_in, const int* in_sizes, int n_in,
                              void* d_out, int out_size, void* d_ws, size_t ws_size,
                              hipStream_t stream) {
    (void)in_sizes; (void)n_in;
    const float* input  = (const float*)d_in[0];
    const float* fskel  = (const float*)d_in[1];
    const float* noise  = (const float*)d_in[2];
    const float* firstW = (const float*)d_in[3];
    const float* firstB = (const float*)d_in[4];
    const float* gWih   = (const float*)d_in[5];
    const float* gWhh   = (const float*)d_in[6];
    const float* gbih   = (const float*)d_in[7];
    const float* gbhh   = (const float*)d_in[8];
    const float* l0W    = (const float*)d_in[9];
    const float* l0b    = (const float*)d_in[10];
    const float* resW   = (const float*)d_in[11];
    const float* resB   = (const float*)d_in[12];
    const float* bnG    = (const float*)d_in[13];
    const float* bnB    = (const float*)d_in[14];
    const float* bnM    = (const float*)d_in[15];
    const float* bnV    = (const float*)d_in[16];
    const float* fl1W   = (const float*)d_in[17];
    const float* fl1b   = (const float*)d_in[18];
    const float* fl2W   = (const float*)d_in[19];
    const float* fl2b   = (const float*)d_in[20];
    const float* fl3W   = (const float*)d_in[21];
    const float* fl3b   = (const float*)d_in[22];
    const float* qkvW   = (const float*)d_in[23];
    const float* pW1    = (const float*)d_in[24];
    const float* pb1    = (const float*)d_in[25];
    const float* pW2    = (const float*)d_in[26];
    const float* pb2    = (const float*)d_in[27];
    const float* aW1    = (const float*)d_in[28];
    const float* ab1    = (const float*)d_in[29];
    const float* aW2    = (const float*)d_in[30];
    float* out = (float*)d_out;

    char* ws = (char*)d_ws;
    Bufs B;
    long MCr = 12800;                         // single chunk if it fits
    if (plan_ws(ws, MCr, B) > ws_size) {
        MCr = 6400;
        if (plan_ws(ws, MCr, B) > ws_size) {  // diagnostic: clean zero output
            hipMemsetAsync(d_out, 0, (size_t)out_size * sizeof(float), stream);
            return;
        }
    }
    const int nchunks = (int)(12800 / MCr);

    // one-time prep
    k_split<<<1152, 256, 0, stream>>>(l0W, B.l0Wh, B.l0Wl, 1024, 267, 288);
    k_split<<<8192, 256, 0, stream>>>(resW, B.resWh, B.resWl, 6144, 1024, 1024);
    k_wc<<<1536, 256, 0, stream>>>(qkvW, fl1W, fl1b, B.WcF, B.bc);
    k_split<<<1536, 256, 0, stream>>>(B.WcF, B.Wch, B.Wcl, 384, 1024, 1024);
    k_split<<<256, 256, 0, stream>>>(aW1, B.aW1b, nullptr, 512, 128, 128);
    k_split<<<256, 256, 0, stream>>>(aW2, B.aW2b, nullptr, 128, 512, 512);
    k_split<<<32, 256, 0, stream>>>(pW2, B.pW2b, nullptr, 128, 64, 64);
    k_sk<<<50, 256, 0, stream>>>(fskel, firstW, firstB, B.sk);
    k_gru<<<256, 64, 0, stream>>>(noise, gWih, gWhh, gbih, gbhh, B.aux);

    for (int c = 0; c < nchunks; ++c) {
        long mbase = (long)c * MCr;
        int xb_grid = (int)((MCr * 288 + 255) / 256);
        k_xbuild<<<xb_grid, 256, 0, stream>>>(input + mbase * 256, B.aux + mbase * 10,
                                              B.sk + mbase, B.xh, B.xl, MCr);
        dim3 gt(8, (unsigned)(MCr / 128));
        k_gemm<0><<<gt, 256, 0, stream>>>(B.xh, B.xl, B.l0Wh, B.l0Wl, 1024, 288,
            nullptr, B.actAh, B.actAl, l0b, nullptr, nullptr, nullptr, nullptr,
            nullptr, nullptr);
        for (int blk = 0; blk < 3; ++blk) {
            int j0 = blk * 2, j1 = blk * 2 + 1;
            k_gemm<1><<<gt, 256, 0, stream>>>(B.actAh, B.actAl,
                B.resWh + (size_t)j0 * 1024 * 1024, B.resWl + (size_t)j0 * 1024 * 1024,
                1024, 1024, nullptr, B.actBh, B.actBl, resB + j0 * 1024,
                bnG + j0 * 1024, bnB + j0 * 1024, bnM + j0 * 1024, bnV + j0 * 1024,
                nullptr, nullptr);
            k_gemm<2><<<gt, 256, 0, stream>>>(B.actBh, B.actBl,
                B.resWh + (size_t)j1 * 1024 * 1024, B.resWl + (size_t)j1 * 1024 * 1024,
                1024, 1024, nullptr, B.actAh, B.actAl, resB + j1 * 1024,
                bnG + j1 * 1024, bnB + j1 * 1024, bnM + j1 * 1024, bnV + j1 * 1024,
                B.actAh, B.actAl);
        }
        dim3 gq(3, (unsigned)(MCr / 128));
        k_gemm<0><<<gq, 256, 0, stream>>>(B.actAh, B.actAl, B.Wch, B.Wcl, 384, 1024,
            B.qkvF, nullptr, nullptr, B.bc, nullptr, nullptr, nullptr, nullptr,
            nullptr, nullptr);
        k_fl2<<<(int)(MCr / 4), 256, 0, stream>>>(B.actAh, B.actAl, fl2W, fl2b, B.posb);
        k_attn<<<(int)MCr, 256, 0, stream>>>(B.qkvF, B.posb, B.aW1b, B.aW2b, ab1, B.pW2b,
                                             pW1, pb1, pb2, fl3W, fl3b, out, mbase);
    }
}

// Round 4
// 1591.425 us; speedup vs baseline: 1.1159x; 1.1159x over previous
//
#include <hip/hip_runtime.h>

typedef __attribute__((ext_vector_type(8))) short bf16x8;
typedef __attribute__((ext_vector_type(4))) float f32x4;
typedef __attribute__((ext_vector_type(4))) ushort u16x4;

__device__ __forceinline__ ushort f2b(float v) {
    union { float f; unsigned u; } x; x.f = v;
    unsigned r = x.u + 0x7fffu + ((x.u >> 16) & 1u);
    return (ushort)(r >> 16);
}
__device__ __forceinline__ float b2f(ushort b) {
    union { float f; unsigned u; } x; x.u = ((unsigned)b) << 16; return x.f;
}

// async global->LDS 16B per lane; LDS dest = wave-uniform base + lane*16
__device__ __forceinline__ void gl_lds16(const void* g, void* l) {
    __builtin_amdgcn_global_load_lds(
        (__attribute__((address_space(1))) void*)(g),
        (__attribute__((address_space(3))) void*)(l), 16, 0, 0);
}

// ---------------- prep kernels ----------------

__global__ void k_split(const float* __restrict__ src, ushort* __restrict__ hi,
                        ushort* __restrict__ lo, int rows, int K, int Kpad) {
    long total = (long)rows * Kpad;
    for (long idx = (long)blockIdx.x * 256 + threadIdx.x; idx < total;
         idx += (long)gridDim.x * 256) {
        int r = (int)(idx / Kpad), c = (int)(idx % Kpad);
        float v = (c < K) ? src[(long)r * K + c] : 0.f;
        ushort h = f2b(v);
        hi[idx] = h;
        if (lo) lo[idx] = f2b(v - b2f(h));
    }
}

// Wc[n][k] = sum_d qkvW[n][d] * fl1W[d][k];  bc[n] = sum_d qkvW[n][d] * fl1b[d]
__global__ void k_wc(const float* __restrict__ qkvW, const float* __restrict__ fl1W,
                     const float* __restrict__ fl1b, float* __restrict__ Wc,
                     float* __restrict__ bc) {
    int idx = blockIdx.x * 256 + threadIdx.x;
    if (idx >= 384 * 1024) return;
    int n = idx >> 10, k = idx & 1023;
    float s = 0.f;
    #pragma unroll 8
    for (int d = 0; d < 128; ++d) s += qkvW[n * 128 + d] * fl1W[d * 1024 + k];
    Wc[idx] = s;
    if (k == 0) {
        float sb = 0.f;
        #pragma unroll 8
        for (int d = 0; d < 128; ++d) sb += qkvW[n * 128 + d] * fl1b[d];
        bc[n] = sb;
    }
}

__global__ void k_sk(const float* __restrict__ fs, const float* __restrict__ fW,
                     const float* __restrict__ fb, float* __restrict__ sk) {
    int m = blockIdx.x * 256 + threadIdx.x;
    if (m >= 12800) return;
    int b = m / 50, i = m % 50;
    float s = fb[i];
    #pragma unroll 4
    for (int c = 0; c < 36; ++c) s += fs[b * 36 + c] * fW[i * 36 + c];
    sk[m] = s;
}

// GRU(10->10): one wave (=one block of 64) per batch element -> 256 CUs covered
__global__ void k_gru(const float* __restrict__ noise, const float* __restrict__ Wih,
                      const float* __restrict__ Whh, const float* __restrict__ bih,
                      const float* __restrict__ bhh, float* __restrict__ aux) {
    int lane = threadIdx.x & 63;
    int b = blockIdx.x;
    if (b >= 256) return;
    float wih[10] = {}, whh[10] = {};
    float bi = 0.f, bh = 0.f;
    if (lane < 30) {
        #pragma unroll
        for (int c = 0; c < 10; ++c) { wih[c] = Wih[lane * 10 + c]; whh[c] = Whh[lane * 10 + c]; }
        bi = bih[lane]; bh = bhh[lane];
    }
    float h = 0.f;
    for (int t = 0; t < 50; ++t) {
        float xr = (lane < 10) ? noise[(b * 50 + t) * 10 + lane] : 0.f;
        float gi = bi, gh = bh;
        #pragma unroll
        for (int c = 0; c < 10; ++c) {
            float xc = __shfl(xr, c, 64);
            float hc = __shfl(h, c, 64);
            gi += wih[c] * xc; gh += whh[c] * hc;
        }
        float siz = __shfl(gi, lane + 10, 64), shz = __shfl(gh, lane + 10, 64);
        float sin_ = __shfl(gi, lane + 20, 64), shn = __shfl(gh, lane + 20, 64);
        float r = 1.f / (1.f + expf(-(gi + gh)));
        float z = 1.f / (1.f + expf(-(siz + shz)));
        float n = tanhf(sin_ + r * shn);
        float hn = (1.f - z) * n + z * h;
        if (lane < 10) { h = hn; aux[(b * 50 + t) * 10 + lane] = tanhf(hn); }
    }
}

__global__ void k_xbuild(const float* __restrict__ input, const float* __restrict__ aux,
                         const float* __restrict__ sk, ushort* __restrict__ xhi,
                         ushort* __restrict__ xlo, long M) {
    long idx = (long)blockIdx.x * 256 + threadIdx.x;
    if (idx >= M * 288) return;
    int m = (int)(idx / 288), c = (int)(idx % 288);
    float v;
    if (c < 256) v = input[(long)m * 256 + c];
    else if (c < 266) v = aux[m * 10 + (c - 256)];
    else if (c == 266) v = sk[m];
    else v = 0.f;
    ushort h = f2b(v);
    xhi[idx] = h;
    xlo[idx] = f2b(v - b2f(h));
}

// ---------------- split-bf16 MFMA GEMM, global_load_lds staging ----------------
// XCD-aware bijective remap (m204): each XCD gets a contiguous wgid range,
// ordered x-fast/y-slow so its B working set stays L2-resident and each
// A-tile is reused by consecutive same-XCD blocks.
template <int MODE>
__global__ __launch_bounds__(256, 3) void k_gemm(
    const ushort* __restrict__ Ahi, const ushort* __restrict__ Alo,
    const ushort* __restrict__ Bhi, const ushort* __restrict__ Blo,
    int N, int K,
    float* outF, ushort* outHi, ushort* outLo,
    const float* __restrict__ bias,
    const float* __restrict__ bng, const float* __restrict__ bnb,
    const float* __restrict__ bnm, const float* __restrict__ bnv,
    const ushort* resHi, const ushort* resLo) {
    __shared__ __align__(16) ushort S[4][128][32];   // Ah, Al, Bh, Bl : 32 KB
    int t = threadIdx.x;
    // XCD swizzle
    int flat = blockIdx.y * gridDim.x + blockIdx.x;
    int nwg = gridDim.x * gridDim.y;
    int q = nwg >> 3, r = nwg & 7;
    int xcd = flat & 7, seq = flat >> 3;
    int wgid = (xcd < r ? xcd * (q + 1) : r * (q + 1) + (xcd - r) * q) + seq;
    int bx = wgid % gridDim.x, by = wgid / gridDim.x;
    int m0 = by * 128, n0 = bx * 128;
    int w = t >> 6, lane = t & 63;
    int wm = w >> 1, wn = w & 1;
    int lo16 = lane & 15, hi4 = lane >> 4;

    const int srow = lane >> 2;
    const int skoff = ((lane & 3) ^ (srow & 3)) * 8;   // elements
    const int slot8 = (hi4 ^ (lo16 & 3)) * 8;

    f32x4 acc[4][4];
    #pragma unroll
    for (int i = 0; i < 4; ++i)
        #pragma unroll
        for (int j = 0; j < 4; ++j) acc[i][j] = f32x4{0.f, 0.f, 0.f, 0.f};

    const int nk = K / 32;
    for (int kt = 0; kt < nk; ++kt) {
        const int kb = kt * 32;
        #pragma unroll
        for (int i = 0; i < 2; ++i) {
            int rg = w * 32 + i * 16;              // wave-uniform row-group base
            long ga = (long)(m0 + rg + srow) * K + kb + skoff;
            long gb = (long)(n0 + rg + srow) * K + kb + skoff;
            gl_lds16(&Ahi[ga], &S[0][rg][0]);
            gl_lds16(&Alo[ga], &S[1][rg][0]);
            gl_lds16(&Bhi[gb], &S[2][rg][0]);
            gl_lds16(&Blo[gb], &S[3][rg][0]);
        }
        __syncthreads();
        bf16x8 ah[4], al[4], bh[4], bl[4];
        #pragma unroll
        for (int m = 0; m < 4; ++m) {
            int row = wm * 64 + m * 16 + lo16;
            ah[m] = *(const bf16x8*)&S[0][row][slot8];
            al[m] = *(const bf16x8*)&S[1][row][slot8];
        }
        #pragma unroll
        for (int n = 0; n < 4; ++n) {
            int col = wn * 64 + n * 16 + lo16;
            bh[n] = *(const bf16x8*)&S[2][col][slot8];
            bl[n] = *(const bf16x8*)&S[3][col][slot8];
        }
        #pragma unroll
        for (int m = 0; m < 4; ++m)
            #pragma unroll
            for (int n = 0; n < 4; ++n) {
                acc[m][n] = __builtin_amdgcn_mfma_f32_16x16x32_bf16(ah[m], bh[n], acc[m][n], 0, 0, 0);
                acc[m][n] = __builtin_amdgcn_mfma_f32_16x16x32_bf16(ah[m], bl[n], acc[m][n], 0, 0, 0);
                acc[m][n] = __builtin_amdgcn_mfma_f32_16x16x32_bf16(al[m], bh[n], acc[m][n], 0, 0, 0);
            }
        __syncthreads();
    }

    #pragma unroll
    for (int n = 0; n < 4; ++n) {
        int gn = n0 + wn * 64 + n * 16 + lo16;
        float bv = bias ? bias[gn] : 0.f;
        float sc = 1.f, sh = 0.f;
        if (MODE >= 1) { sc = bng[gn] * rsqrtf(bnv[gn] + 1e-5f); sh = bnb[gn] - bnm[gn] * sc; }
        #pragma unroll
        for (int m = 0; m < 4; ++m)
            #pragma unroll
            for (int r2 = 0; r2 < 4; ++r2) {
                int gm = m0 + wm * 64 + m * 16 + hi4 * 4 + r2;
                long o = (long)gm * N + gn;
                float v = acc[m][n][r2] + bv;
                if (MODE >= 1) v = fmaxf(v * sc + sh, 0.f);
                if (MODE == 2) v += b2f(resHi[o]) + b2f(resLo[o]);
                if (outF) outF[o] = v;
                if (outHi) {
                    ushort hb = f2b(v);
                    outHi[o] = hb;
                    outLo[o] = f2b(v - b2f(hb));
                }
            }
    }
}

// ---------------- pos (fl2): wave-per-row, vectorized hi/lo loads ----------------
__global__ void k_fl2(const ushort* __restrict__ hA, const ushort* __restrict__ lA,
                      const float* __restrict__ W, const float* __restrict__ bias,
                      float* __restrict__ pos) {
    int w = threadIdx.x >> 6, lane = threadIdx.x & 63;
    int m = blockIdx.x * 4 + w;
    float a0 = 0.f, a1 = 0.f, a2 = 0.f;
    for (int k0 = lane * 4; k0 < 1024; k0 += 256) {
        long o = (long)m * 1024 + k0;
        u16x4 hv = *(const u16x4*)&hA[o];
        u16x4 lv = *(const u16x4*)&lA[o];
        f32x4 w0 = *(const f32x4*)&W[k0];
        f32x4 w1 = *(const f32x4*)&W[1024 + k0];
        f32x4 w2 = *(const f32x4*)&W[2048 + k0];
        #pragma unroll
        for (int e = 0; e < 4; ++e) {
            float x = b2f(hv[e]) + b2f(lv[e]);
            a0 += x * w0[e]; a1 += x * w1[e]; a2 += x * w2[e];
        }
    }
    #pragma unroll
    for (int off = 32; off; off >>= 1) {
        a0 += __shfl_xor(a0, off, 64);
        a1 += __shfl_xor(a1, off, 64);
        a2 += __shfl_xor(a2, off, 64);
    }
    if (lane == 0) {
        pos[m * 3 + 0] = a0 + bias[0];
        pos[m * 3 + 1] = a1 + bias[1];
        pos[m * 3 + 2] = a2 + bias[2];
    }
}

// ---------------- fused attention (+rel_emb +fl3) per (b,i) block ----------------
// R9: R0's proven main-loop math (col-split GEMM1: wave owns 16 cols, 4 bv
// loads/e8 each reused 4x; A-frags from XS LDS; identical GEMM2) plus two
// mechanically-safe deltas:
//  (a) HE double-buffered (2x8KB @32K..48K, XS stays live @16K..32K):
//      removes the first barrier of each e8 (16 -> 8 in main loop).
//      Safety: buffer reused at iter k+2; barrier(k+1) separates.
//  (b) T14 issue-early/use-late: GEMM2's 4 bfv loads and NEXT e8's 4 bv
//      loads issue BEFORE the barrier; __syncthreads' vmcnt(0) drain
//      completes them behind the barrier wait -> both GEMMs start with B
//      in registers. +32 VGPR transient; peak ~158 unified < 170 cap.
// NO A-register hoist (R2/R3 lesson: spill / reuse loss).
// LDS map (48KB -> 3 blocks/CU):
//   [0,16384)      REL[64][256B pitch], swz byte = j*256 + ((d*2)^((j&15)<<4))
//   [16384,32768)  XS[64][256B pitch] (alive all loop), same swz
//   [32768,49152)  HE ping-pong (2 x 64 rows x 128B, swz (c*2)^((r&7)<<4))
//   aggF f32[128] overlaid at 16384 after main loop (XS dead by then).
__global__ __launch_bounds__(256, 3) void k_attn(
    const float* __restrict__ qkv, const float* __restrict__ posb,
    const ushort* __restrict__ W1b, const ushort* __restrict__ W2b,
    const float* __restrict__ b1, const ushort* __restrict__ pW2b,
    const float* __restrict__ pW1, const float* __restrict__ pb1,
    const float* __restrict__ pb2,
    const float* __restrict__ fl3W, const float* __restrict__ fl3b,
    float* __restrict__ out, long mbase) {
    __shared__ __align__(16) char smem[49152];
    // XCD-aware swizzle: gridDim.x % 8 == 0 always (12800 or 6400)
    int cpx = gridDim.x >> 3;
    int biL = (blockIdx.x & 7) * cpx + (blockIdx.x >> 3);
    int bL = biL / 50;
    int t = threadIdx.x, w = t >> 6, lane = t & 63;
    int lo16 = lane & 15, hi4 = lane >> 4;

    // ---- phase 0a: h1 fragments in registers (row-split, wave-private) ----
    // lane holds h1[jrow][k] for jrow = w*16+lo16, k = kt*32 + hi4*8 + e
    bf16x8 h_a[2];
    {
        const int jrow = w * 16 + lo16;
        const bool jvalid = jrow < 50;
        float pi0 = posb[biL * 3], pi1 = posb[biL * 3 + 1], pi2 = posb[biL * 3 + 2];
        float d0 = 0.f, d1 = 0.f, d2 = 0.f;
        if (jvalid) {
            int pj = (bL * 50 + jrow) * 3;
            d0 = pi0 - posb[pj]; d1 = pi1 - posb[pj + 1]; d2 = pi2 - posb[pj + 2];
        }
        #pragma unroll
        for (int kt = 0; kt < 2; ++kt)
            #pragma unroll
            for (int e = 0; e < 8; ++e) {
                int ke = kt * 32 + hi4 * 8 + e;
                float v = 0.f;
                if (jvalid)
                    v = fmaxf(pb1[ke] + pW1[ke * 3] * d0 + pW1[ke * 3 + 1] * d1
                              + pW1[ke * 3 + 2] * d2, 0.f);
                h_a[kt][e] = (short)f2b(v);
            }
    }

    // ---- phase 0b: rel rows for own 16 j (MFMA K=64) -> REL (wave-private) ----
    {
        f32x4 racc[8];
        #pragma unroll
        for (int n = 0; n < 8; ++n) racc[n] = f32x4{0.f, 0.f, 0.f, 0.f};
        #pragma unroll
        for (int kt = 0; kt < 2; ++kt) {
            int k0 = kt * 32 + hi4 * 8;
            #pragma unroll
            for (int n = 0; n < 8; ++n) {
                bf16x8 bv = *(const bf16x8*)&pW2b[(n * 16 + lo16) * 64 + k0];
                racc[n] = __builtin_amdgcn_mfma_f32_16x16x32_bf16(h_a[kt], bv, racc[n], 0, 0, 0);
            }
        }
        #pragma unroll
        for (int n = 0; n < 8; ++n) {
            int col = n * 16 + lo16;
            float pb = pb2[col];
            #pragma unroll
            for (int r = 0; r < 4; ++r) {
                int j = w * 16 + hi4 * 4 + r;
                *(ushort*)(smem + j * 256 + ((col * 2) ^ ((j & 15) << 4))) =
                    f2b(racc[n][r] + pb);
            }
        }
    }

    // prefetch GEMM1 B for e8=0 (latency hidden under X-build + barriers)
    bf16x8 bv[4];
    #pragma unroll
    for (int kt = 0; kt < 4; ++kt)
        bv[kt] = *(const bf16x8*)&W1b[(w * 16 + lo16) * 128 + kt * 32 + hi4 * 8];

    __syncthreads();   // REL complete (X-build reads rows written by other waves)

    // ---- phase 1: X = q_i - k_j + rel -> XS @16K (bf16 swz); rows 50..63 zero ----
    #pragma unroll
    for (int cc = 0; cc < 4; ++cc) {
        int c = cc * 256 + t;
        int row = c >> 4, g = c & 15;
        bf16x8 tv;
        if (row < 50) {
            long kq = (long)biL * 384;
            long kk = (long)(bL * 50 + row) * 384 + 128;
            bf16x8 rv = *(const bf16x8*)(smem + row * 256 + ((g * 16) ^ ((row & 15) << 4)));
            #pragma unroll
            for (int e = 0; e < 8; ++e) {
                int col = g * 8 + e;
                float v = qkv[kq + col] - qkv[kk + col] + b2f((ushort)rv[e]);
                tv[e] = (short)f2b(v);
            }
        } else {
            #pragma unroll
            for (int e = 0; e < 8; ++e) tv[e] = 0;
        }
        *(bf16x8*)(smem + 16384 + row * 256 + ((g * 16) ^ ((row & 15) << 4))) = tv;
    }
    __syncthreads();   // XS complete

    // ---- main loop: 8 eighths of H, ONE barrier each ----
    f32x4 acc2[4][2];
    #pragma unroll
    for (int m = 0; m < 4; ++m)
        #pragma unroll
        for (int n = 0; n < 2; ++n) acc2[m][n] = f32x4{0.f, 0.f, 0.f, 0.f};

    #pragma unroll 1
    for (int e8 = 0; e8 < 8; ++e8) {
        char* HEb = smem + 32768 + (e8 & 1) * 8192;
        // GEMM1: H[:, wave's 16 cols of e8], K=128; A from XS LDS, bv preloaded
        f32x4 acc1[4];
        #pragma unroll
        for (int m = 0; m < 4; ++m) acc1[m] = f32x4{0.f, 0.f, 0.f, 0.f};
        __builtin_amdgcn_s_setprio(1);
        #pragma unroll
        for (int kt = 0; kt < 4; ++kt) {
            int k0 = kt * 32 + hi4 * 8;
            #pragma unroll
            for (int m = 0; m < 4; ++m) {
                int row = m * 16 + lo16;
                bf16x8 af = *(const bf16x8*)(smem + 16384 + row * 256 +
                              ((k0 * 2) ^ ((row & 15) << 4)));
                acc1[m] = __builtin_amdgcn_mfma_f32_16x16x32_bf16(af, bv[kt], acc1[m], 0, 0, 0);
            }
        }
        __builtin_amdgcn_s_setprio(0);
        // prefetch GEMM2 B for THIS e8 (completes at the barrier drain)
        bf16x8 bfv2[2][2];
        #pragma unroll
        for (int kt2 = 0; kt2 < 2; ++kt2)
            #pragma unroll
            for (int n = 0; n < 2; ++n)
                bfv2[kt2][n] = *(const bf16x8*)&W2b[
                    (long)(w * 32 + n * 16 + lo16) * 512 + e8 * 64 + kt2 * 32 + hi4 * 8];
        // bias + relu -> HE[buf] (wave's 16 cols)
        {
            int ch = w * 16 + lo16;
            float bb = b1[e8 * 64 + ch];
            #pragma unroll
            for (int m = 0; m < 4; ++m)
                #pragma unroll
                for (int r = 0; r < 4; ++r) {
                    int row = m * 16 + hi4 * 4 + r;
                    float v = fmaxf(acc1[m][r] + bb, 0.f);
                    *(ushort*)(HEb + row * 128 + ((ch * 2) ^ ((row & 7) << 4))) = f2b(v);
                }
        }
        // prefetch NEXT e8's GEMM1 B (completes at the barrier drain)
        if (e8 < 7) {
            #pragma unroll
            for (int kt = 0; kt < 4; ++kt)
                bv[kt] = *(const bf16x8*)&W1b[
                    ((e8 + 1) * 64 + w * 16 + lo16) * 128 + kt * 32 + hi4 * 8];
        }
        __syncthreads();   // HE[buf] ready; all prefetches drained (vmcnt(0))
        // GEMM2 partial: K chunk [e8*64, e8*64+64)
        #pragma unroll
        for (int kt2 = 0; kt2 < 2; ++kt2) {
            bf16x8 af2[4];
            #pragma unroll
            for (int m = 0; m < 4; ++m) {
                int row = m * 16 + lo16;
                af2[m] = *(const bf16x8*)(HEb + row * 128 +
                          (((kt2 * 32 + hi4 * 8) * 2) ^ ((row & 7) << 4)));
            }
            __builtin_amdgcn_s_setprio(1);
            #pragma unroll
            for (int n = 0; n < 2; ++n)
                #pragma unroll
                for (int m = 0; m < 4; ++m)
                    acc2[m][n] = __builtin_amdgcn_mfma_f32_16x16x32_bf16(af2[m], bfv2[kt2][n], acc2[m][n], 0, 0, 0);
            __builtin_amdgcn_s_setprio(0);
        }
    }

    // ---- softmax over j + agg (v_ij = v + rel, rel from REL @0) ----
    float outv[2];
    #pragma unroll
    for (int n = 0; n < 2; ++n) {
        float mx = -1e30f;
        #pragma unroll
        for (int m = 0; m < 4; ++m)
            #pragma unroll
            for (int r = 0; r < 4; ++r) {
                int j = m * 16 + hi4 * 4 + r;
                if (j < 50) mx = fmaxf(mx, acc2[m][n][r]);
            }
        mx = fmaxf(mx, __shfl_xor(mx, 16, 64));
        mx = fmaxf(mx, __shfl_xor(mx, 32, 64));
        float e[4][4];
        float sum = 0.f;
        #pragma unroll
        for (int m = 0; m < 4; ++m)
            #pragma unroll
            for (int r = 0; r < 4; ++r) {
                int j = m * 16 + hi4 * 4 + r;
                float ev = (j < 50) ? __expf(acc2[m][n][r] - mx) : 0.f;
                e[m][r] = ev; sum += ev;
            }
        sum += __shfl_xor(sum, 16, 64);
        sum += __shfl_xor(sum, 32, 64);
        float inv = 1.f / sum;
        int col = w * 32 + n * 16 + lo16;
        float ag = 0.f;
        #pragma unroll
        for (int m = 0; m < 4; ++m)
            #pragma unroll
            for (int r = 0; r < 4; ++r) {
                int j = m * 16 + hi4 * 4 + r;
                if (j < 50) {
                    float rl = b2f(*(const ushort*)(smem + j * 256 +
                                  ((col * 2) ^ ((j & 15) << 4))));
                    float vv = qkv[(long)(bL * 50 + j) * 384 + 256 + col] + rl;
                    ag += e[m][r] * inv * vv;
                }
            }
        ag += __shfl_xor(ag, 16, 64);
        ag += __shfl_xor(ag, 32, 64);
        outv[n] = ag;
    }
    float* aggF = (float*)(smem + 16384);
    if (hi4 == 0) {
        aggF[w * 32 + lo16] = outv[0];
        aggF[w * 32 + 16 + lo16] = outv[1];
    }
    __syncthreads();

    // fused fl3 + tanh
    if (t < 36) {
        float s = fl3b[t];
        const float* wf = &fl3W[t * 128];
        #pragma unroll 8
        for (int d = 0; d < 128; ++d) s += aggF[d] * wf[d];
        out[(mbase + biL) * 36 + t] = tanhf(s);
    }
}

// ---------------- launch ----------------
struct Bufs {
    float *sk, *aux, *qkvF, *posb, *WcF, *bc;
    ushort *xh, *xl, *actAh, *actAl, *actBh, *actBl;
    ushort *l0Wh, *l0Wl, *resWh, *resWl, *Wch, *Wcl, *aW1b, *aW2b, *pW2b;
};

static size_t plan_ws(char* ws, long MCr, Bufs& B) {
    size_t off = 0;
    auto alloc = [&](size_t n) { char* p = ws + off; off += (n + 255) & ~(size_t)255; return p; };
    B.sk    = (float*) alloc(12800L * 4);
    B.aux   = (float*) alloc(128000L * 4);
    B.xh    = (ushort*)alloc((size_t)MCr * 288 * 2);
    B.xl    = (ushort*)alloc((size_t)MCr * 288 * 2);
    B.actAh = (ushort*)alloc((size_t)MCr * 1024 * 2);
    B.actAl = (ushort*)alloc((size_t)MCr * 1024 * 2);
    B.actBh = (ushort*)alloc((size_t)MCr * 1024 * 2);
    B.actBl = (ushort*)alloc((size_t)MCr * 1024 * 2);
    B.qkvF  = (float*) alloc((size_t)MCr * 384 * 4);
    B.posb  = (float*) alloc((size_t)MCr * 3 * 4);
    B.l0Wh  = (ushort*)alloc(1024L * 288 * 2);
    B.l0Wl  = (ushort*)alloc(1024L * 288 * 2);
    B.resWh = (ushort*)alloc(6144L * 1024 * 2);
    B.resWl = (ushort*)alloc(6144L * 1024 * 2);
    B.WcF   = (float*) alloc(384L * 1024 * 4);
    B.Wch   = (ushort*)alloc(384L * 1024 * 2);
    B.Wcl   = (ushort*)alloc(384L * 1024 * 2);
    B.bc    = (float*) alloc(384L * 4);
    B.aW1b  = (ushort*)alloc(512L * 128 * 2);
    B.aW2b  = (ushort*)alloc(128L * 512 * 2);
    B.pW2b  = (ushort*)alloc(128L * 64 * 2);
    return off;
}

extern "C" void kernel_launch(void* const* d_in, const int* in_sizes, int n_in,
                              void* d_out, int out_size, void* d_ws, size_t ws_size,
                              hipStream_t stream) {
    (void)in_sizes; (void)n_in;
    const float* input  = (const float*)d_in[0];
    const float* fskel  = (const float*)d_in[1];
    const float* noise  = (const float*)d_in[2];
    const float* firstW = (const float*)d_in[3];
    const float* firstB = (const float*)d_in[4];
    const float* gWih   = (const float*)d_in[5];
    const float* gWhh   = (const float*)d_in[6];
    const float* gbih   = (const float*)d_in[7];
    const float* gbhh   = (const float*)d_in[8];
    const float* l0W    = (const float*)d_in[9];
    const float* l0b    = (const float*)d_in[10];
    const float* resW   = (const float*)d_in[11];
    const float* resB   = (const float*)d_in[12];
    const float* bnG    = (const float*)d_in[13];
    const float* bnB    = (const float*)d_in[14];
    const float* bnM    = (const float*)d_in[15];
    const float* bnV    = (const float*)d_in[16];
    const float* fl1W   = (const float*)d_in[17];
    const float* fl1b   = (const float*)d_in[18];
    const float* fl2W   = (const float*)d_in[19];
    const float* fl2b   = (const float*)d_in[20];
    const float* fl3W   = (const float*)d_in[21];
    const float* fl3b   = (const float*)d_in[22];
    const float* qkvW   = (const float*)d_in[23];
    const float* pW1    = (const float*)d_in[24];
    const float* pb1    = (const float*)d_in[25];
    const float* pW2    = (const float*)d_in[26];
    const float* pb2    = (const float*)d_in[27];
    const float* aW1    = (const float*)d_in[28];
    const float* ab1    = (const float*)d_in[29];
    const float* aW2    = (const float*)d_in[30];
    float* out = (float*)d_out;

    char* ws = (char*)d_ws;
    Bufs B;
    long MCr = 12800;                         // single chunk if it fits
    if (plan_ws(ws, MCr, B) > ws_size) {
        MCr = 6400;
        if (plan_ws(ws, MCr, B) > ws_size) {  // diagnostic: clean zero output
            hipMemsetAsync(d_out, 0, (size_t)out_size * sizeof(float), stream);
            return;
        }
    }
    const int nchunks = (int)(12800 / MCr);

    // one-time prep
    k_split<<<1152, 256, 0, stream>>>(l0W, B.l0Wh, B.l0Wl, 1024, 267, 288);
    k_split<<<8192, 256, 0, stream>>>(resW, B.resWh, B.resWl, 6144, 1024, 1024);
    k_wc<<<1536, 256, 0, stream>>>(qkvW, fl1W, fl1b, B.WcF, B.bc);
    k_split<<<1536, 256, 0, stream>>>(B.WcF, B.Wch, B.Wcl, 384, 1024, 1024);
    k_split<<<256, 256, 0, stream>>>(aW1, B.aW1b, nullptr, 512, 128, 128);
    k_split<<<256, 256, 0, stream>>>(aW2, B.aW2b, nullptr, 128, 512, 512);
    k_split<<<32, 256, 0, stream>>>(pW2, B.pW2b, nullptr, 128, 64, 64);
    k_sk<<<50, 256, 0, stream>>>(fskel, firstW, firstB, B.sk);
    k_gru<<<256, 64, 0, stream>>>(noise, gWih, gWhh, gbih, gbhh, B.aux);

    for (int c = 0; c < nchunks; ++c) {
        long mbase = (long)c * MCr;
        int xb_grid = (int)((MCr * 288 + 255) / 256);
        k_xbuild<<<xb_grid, 256, 0, stream>>>(input + mbase * 256, B.aux + mbase * 10,
                                              B.sk + mbase, B.xh, B.xl, MCr);
        dim3 gt(8, (unsigned)(MCr / 128));
        k_gemm<0><<<gt, 256, 0, stream>>>(B.xh, B.xl, B.l0Wh, B.l0Wl, 1024, 288,
            nullptr, B.actAh, B.actAl, l0b, nullptr, nullptr, nullptr, nullptr,
            nullptr, nullptr);
        for (int blk = 0; blk < 3; ++blk) {
            int j0 = blk * 2, j1 = blk * 2 + 1;
            k_gemm<1><<<gt, 256, 0, stream>>>(B.actAh, B.actAl,
                B.resWh + (size_t)j0 * 1024 * 1024, B.resWl + (size_t)j0 * 1024 * 1024,
                1024, 1024, nullptr, B.actBh, B.actBl, resB + j0 * 1024,
                bnG + j0 * 1024, bnB + j0 * 1024, bnM + j0 * 1024, bnV + j0 * 1024,
                nullptr, nullptr);
            k_gemm<2><<<gt, 256, 0, stream>>>(B.actBh, B.actBl,
                B.resWh + (size_t)j1 * 1024 * 1024, B.resWl + (size_t)j1 * 1024 * 1024,
                1024, 1024, nullptr, B.actAh, B.actAl, resB + j1 * 1024,
                bnG + j1 * 1024, bnB + j1 * 1024, bnM + j1 * 1024, bnV + j1 * 1024,
                B.actAh, B.actAl);
        }
        dim3 gq(3, (unsigned)(MCr / 128));
        k_gemm<0><<<gq, 256, 0, stream>>>(B.actAh, B.actAl, B.Wch, B.Wcl, 384, 1024,
            B.qkvF, nullptr, nullptr, B.bc, nullptr, nullptr, nullptr, nullptr,
            nullptr, nullptr);
        k_fl2<<<(int)(MCr / 4), 256, 0, stream>>>(B.actAh, B.actAl, fl2W, fl2b, B.posb);
        k_attn<<<(int)MCr, 256, 0, stream>>>(B.qkvF, B.posb, B.aW1b, B.aW2b, ab1, B.pW2b,
                                             pW1, pb1, pb2, fl3W, fl3b, out, mbase);
    }
}